// Round 19
// baseline (55.386 us; speedup 1.0000x reference)
//
#include <hip/hip_runtime.h>
#include <hip/hip_bf16.h>

// DCNv2 fwd — R18: R17's extreme-TLP config with the spill bug fixed.
// 1-wave (64-thread) blocks, zero barriers, 2KB LDS; launch_bounds(64,4)
// -> VGPR cap 128 (R17's (64,8) forced VGPR=32 -> ~0.5GB scratch traffic,
// FETCH 296MB/WRITE 283MB; occupancy 46.5% proved the TLP mechanism works).
// Grid 4608 = 18 waves/CU supply; resource ceiling 16 waves/CU.
// B=8, C=64, H=W=96, O=64, K=3, s=1, p=1, d=1, DG=1 -> Ho=Wo=96.

#define B_   8
#define C_   64
#define H_   96
#define W_   96
#define O_   64
#define KK_  9
#define HW_  (H_ * W_)          // 9216
#define NT16 (HW_ / 16)         // 576 tiles of 16 px per image
#define PW_  104                // padded width/height (halo: interior at +2)
#define PHW_ (PW_ * PW_)        // 10816
#define ROWB (PW_ * C_ * 2)     // padded row stride bytes = 13312

typedef __attribute__((ext_vector_type(8))) short short8;     // 8 bf16
typedef __attribute__((ext_vector_type(4))) float f32x4;
typedef __attribute__((ext_vector_type(4))) unsigned uint4v;

__device__ __forceinline__ unsigned short f2bf(float f) {
    union { float f; unsigned u; } v; v.f = f;
    unsigned r = v.u + 0x7FFF + ((v.u >> 16) & 1);   // RNE
    return (unsigned short)(r >> 16);
}
__device__ __forceinline__ float bflo(unsigned u) {
    union { unsigned u; float f; } v; v.u = u << 16; return v.f;
}
__device__ __forceinline__ float bfhi(unsigned u) {
    union { unsigned u; float f; } v; v.u = u & 0xffff0000u; return v.f;
}
__device__ __forceinline__ unsigned packbf2(float lo, float hi) {
    __hip_bfloat162 h = __float22bfloat162_rn(make_float2(lo, hi));
    union { __hip_bfloat162 h; unsigned u; } v; v.h = h; return v.u;
}

// ---- converter: x NCHW f32 -> PADDED NHWC bf16 (zero halo);
//      blocks 0..15 also emit fragment-ordered bf16 weights ----
__global__ __launch_bounds__(256)
void cvt_kernel(const float* __restrict__ x, const float* __restrict__ wgt,
                unsigned short* __restrict__ xP, unsigned short* __restrict__ wsb)
{
    const int t = threadIdx.x;
    if (blockIdx.x < 16) {
        int i = blockIdx.x * 256 + t;      // (o,c) over 4096
        int o = i >> 6, c = i & 63;
        int ks = c >> 5, hi = (c >> 3) & 3, j = c & 7;
        #pragma unroll
        for (int kk = 0; kk < KK_; ++kk)
            wsb[(size_t)(((kk*2 + ks)*4 + hi)*64 + o)*8 + j] =
                f2bf(wgt[(size_t)(o*64 + c)*KK_ + kk]);
    }
    const int b = blockIdx.x & 7;                  // XCD-pinned
    const int p = (blockIdx.x >> 3) * 256 + t;     // padded pixel id
    if (p >= PHW_) return;
    const int py = p / PW_, px = p % PW_;
    const bool interior = (py >= 2) & (py < 2 + H_) & (px >= 2) & (px < 2 + W_);
    const int sp = (py - 2) * W_ + (px - 2);
    const float* xs = x + (size_t)b * C_ * HW_ + sp;
    unsigned pk[32];
    #pragma unroll
    for (int c2 = 0; c2 < 32; ++c2)
        pk[c2] = interior ? packbf2(xs[(size_t)(2*c2) * HW_],
                                    xs[(size_t)(2*c2+1) * HW_]) : 0u;
    uint4v* dst = (uint4v*)(xP + ((size_t)b * PHW_ + p) * C_);
    #pragma unroll
    for (int j = 0; j < 8; ++j) {
        uint4v v;
        v.x = pk[4*j]; v.y = pk[4*j+1]; v.z = pk[4*j+2]; v.w = pk[4*j+3];
        dst[j] = v;
    }
}

// 1 wave per block. LDS = 2048 B wave staging only ([16 px][128 B], XOR-swz),
// single-buffered (in-order per-wave DS pipe -> WAR-safe, zero barriers).
__global__ __launch_bounds__(64, 4)
void dcn_mfma(const unsigned short* __restrict__ xP,
              const float* __restrict__ offs, const float* __restrict__ mask,
              const unsigned short* __restrict__ wsb,
              const float* __restrict__ bias, float* __restrict__ out)
{
    __shared__ __align__(16) char stg[2048];

    const int lane = threadIdx.x;                  // 0..63
    const int bi   = blockIdx.x & 7;               // XCD-pinned
    const int pixbase = (blockIdx.x >> 3) * 16;    // 576 tiles/img

    const int lr = lane & 15, lg = lane >> 4;      // MFMA fragment coords
    const int s   = lane & 7;                      // 16B slice within line
    const int ph0 = lane >> 3;                     // sample pixel (h=0); +8 h=1
    const int pix0 = pixbase + ph0;

    const float* offB = offs + (size_t)bi * 18 * HW_;
    const float* mB   = mask + (size_t)bi * 9  * HW_;
    const unsigned short* xB = xP + (size_t)bi * PHW_ * C_ + s * 8;

    f32x4 acc[4] = {};                             // 4 o-tiles x (16o x 16px)

    // coords for current kk, both pixel halves
    float cy[2], cx[2], cm[2];
    #pragma unroll
    for (int h = 0; h < 2; ++h) {
        cy[h] = offB[pix0 + h * 8];
        cx[h] = offB[HW_ + pix0 + h * 8];
        cm[h] = mB[pix0 + h * 8];
    }

    #pragma unroll 1
    for (int kk = 0; kk < KK_; ++kk) {
        // ---- geometry + corner loads (halo: no masks, const offsets) ----
        uint4v cor[2][4];
        float  w4[2][4];
        #pragma unroll
        for (int h = 0; h < 2; ++h) {
            int pixg = pix0 + h * 8;
            int ho = pixg / W_, wo = pixg % W_;
            float py  = (float)(ho - 1 + kk / 3) + cy[h];
            float pxf = (float)(wo - 1 + kk % 3) + cx[h];
            float y0f = floorf(py), x0f = floorf(pxf);
            float ly = py - y0f, lx = pxf - x0f;
            int y0 = min(max((int)y0f, -2), H_ + 1);   // halo-clamped
            int x0 = min(max((int)x0f, -2), W_ + 1);
            float hy = 1.f - ly, hx = 1.f - lx;
            float a = cm[h] * hy, b2 = cm[h] * ly;
            w4[h][0] = a * hx;  w4[h][1] = a * lx;
            w4[h][2] = b2 * hx; w4[h][3] = b2 * lx;
            const char* cb = (const char*)(xB +
                (size_t)((y0 + 2) * PW_ + (x0 + 2)) * C_);
            cor[h][0] = *(const uint4v*)(cb);
            cor[h][1] = *(const uint4v*)(cb + 128);
            cor[h][2] = *(const uint4v*)(cb + ROWB);
            cor[h][3] = *(const uint4v*)(cb + ROWB + 128);
        }

        // ---- A-frags(kk) from fragment-ordered global (L1/L2-hot) ----
        short8 af[8];
        #pragma unroll
        for (int ks = 0; ks < 2; ++ks)
            #pragma unroll
            for (int m = 0; m < 4; ++m)
                af[ks*4 + m] = *(const short8*)(wsb +
                    (size_t)((((kk*2 + ks)*4 + lg)*64) + m*16 + lr) * 8);

        // ---- coords prefetch kk+1 ----
        if (kk + 1 < KK_) {
            #pragma unroll
            for (int h = 0; h < 2; ++h) {
                cy[h] = offB[(size_t)(2*kk + 2) * HW_ + pix0 + h * 8];
                cx[h] = offB[(size_t)(2*kk + 3) * HW_ + pix0 + h * 8];
                cm[h] = mB[(size_t)(kk + 1) * HW_ + pix0 + h * 8];
            }
        }

        // ---- lerp (lane-local slice) + pack + swizzled ds_write ----
        #pragma unroll
        for (int h = 0; h < 2; ++h) {
            float w00 = w4[h][0], w01 = w4[h][1];
            float w10 = w4[h][2], w11 = w4[h][3];
            uint4v pk4;
            #pragma unroll
            for (int j = 0; j < 4; ++j) {
                unsigned u0 = cor[h][0][j], u1 = cor[h][1][j];
                unsigned u2 = cor[h][2][j], u3 = cor[h][3][j];
                float lo = fmaf(bflo(u0), w00, fmaf(bflo(u1), w01,
                           fmaf(bflo(u2), w10, bflo(u3) * w11)));
                float hi = fmaf(bfhi(u0), w00, fmaf(bfhi(u1), w01,
                           fmaf(bfhi(u2), w10, bfhi(u3) * w11)));
                pk4[j] = packbf2(lo, hi);
            }
            int pxl = ph0 + h * 8;
            *(uint4v*)(stg + pxl * 128 + ((s * 16) ^ ((pxl & 7) << 4))) = pk4;
        }

        // ---- B-frags (own-wave LDS, in-order DS pipe) + MFMA ----
        union { uint4v u; short8 s8; } b0, b1;
        b0.u = *(const uint4v*)(stg + lr*128 + ((lg*16     ) ^ ((lr & 7) << 4)));
        b1.u = *(const uint4v*)(stg + lr*128 + ((64 + lg*16) ^ ((lr & 7) << 4)));
        #pragma unroll
        for (int m = 0; m < 4; ++m)
            acc[m] = __builtin_amdgcn_mfma_f32_16x16x32_bf16(af[m],     b0.s8, acc[m], 0, 0, 0);
        #pragma unroll
        for (int m = 0; m < 4; ++m)
            acc[m] = __builtin_amdgcn_mfma_f32_16x16x32_bf16(af[4 + m], b1.s8, acc[m], 0, 0, 0);
    }

    // ---- epilogue: direct stores (no barrier; 64B-granule accepted) ----
    // C/D layout: col px = lr, row o = m*16 + lg*4 + r
    #pragma unroll
    for (int m = 0; m < 4; ++m) {
        #pragma unroll
        for (int r = 0; r < 4; ++r) {
            int o = m * 16 + lg * 4 + r;
            out[((size_t)bi * O_ + o) * HW_ + pixbase + lr] = acc[m][r] + bias[o];
        }
    }
}

extern "C" void kernel_launch(void* const* d_in, const int* in_sizes, int n_in,
                              void* d_out, int out_size, void* d_ws, size_t ws_size,
                              hipStream_t stream)
{
    const float* x    = (const float*)d_in[0];
    const float* offs = (const float*)d_in[1];
    const float* mask = (const float*)d_in[2];
    const float* wgt  = (const float*)d_in[3];
    const float* bias = (const float*)d_in[4];
    float* out = (float*)d_out;

    unsigned short* xP  = (unsigned short*)d_ws;                      // 11,075,584 B
    unsigned short* wsb = (unsigned short*)((char*)d_ws + 11534336);  // 73,728 B

    hipLaunchKernelGGL(cvt_kernel, dim3(8 * 43), dim3(256), 0, stream,
                       x, wgt, xP, wsb);
    hipLaunchKernelGGL(dcn_mfma, dim3(8 * NT16), dim3(64), 0, stream,
                       xP, offs, mask, wsb, bias, out);
}

// Round 20
// 46.276 us; speedup vs baseline: 1.1968x; 1.1968x over previous
//
#include <hip/hip_runtime.h>
#include <hip/hip_bf16.h>

// DCNv2 fwd — R20: R12 skeleton + CROSS-BARRIER register prefetch of corners.
// Corners(kk+1) issued into VGPRs BEFORE iter-kk's __syncthreads: the
// barrier's vmcnt(0) drain COMPLETES them while iter kk's lerp/MFMA/stage
// runs -> iter kk+1 starts with corner data already in registers (zero
// exposed gather latency). launch_bounds(256,2): VGPR cap 256 >> ~170 live,
// so regalloc has no pressure reason to sink the prefetch (R6/R7 failure
// mode); sched_barrier(0) pins the issue point; loop fully unrolled so
// dbuf indices are compile-time. Weight-stage loads issue BEFORE corner
// loads so their ds_write's counted vmcnt doesn't wait on corners.
// B=8, C=64, H=W=96, O=64, K=3, s=1, p=1, d=1, DG=1 -> Ho=Wo=96.

#define B_   8
#define C_   64
#define H_   96
#define W_   96
#define O_   64
#define KK_  9
#define HW_  (H_ * W_)          // 9216
#define NTILE (HW_ / 64)        // 144
#define PW_  104                // padded width/height (halo: interior at +2)
#define PHW_ (PW_ * PW_)        // 10816
#define ROWB (PW_ * C_ * 2)     // padded row stride bytes = 13312

typedef __attribute__((ext_vector_type(8))) short short8;     // 8 bf16
typedef __attribute__((ext_vector_type(4))) float f32x4;
typedef __attribute__((ext_vector_type(4))) unsigned uint4v;

__device__ __forceinline__ unsigned short f2bf(float f) {
    union { float f; unsigned u; } v; v.f = f;
    unsigned r = v.u + 0x7FFF + ((v.u >> 16) & 1);   // RNE
    return (unsigned short)(r >> 16);
}
__device__ __forceinline__ float bflo(unsigned u) {
    union { unsigned u; float f; } v; v.u = u << 16; return v.f;
}
__device__ __forceinline__ float bfhi(unsigned u) {
    union { unsigned u; float f; } v; v.u = u & 0xffff0000u; return v.f;
}
__device__ __forceinline__ unsigned packbf2(float lo, float hi) {
    __hip_bfloat162 h = __float22bfloat162_rn(make_float2(lo, hi));
    union { __hip_bfloat162 h; unsigned u; } v; v.h = h; return v.u;
}

// ---- converter: x NCHW f32 -> PADDED NHWC bf16 (zero halo);
//      blocks 0..15 also emit fragment-ordered bf16 weights ----
__global__ __launch_bounds__(256)
void cvt_kernel(const float* __restrict__ x, const float* __restrict__ wgt,
                unsigned short* __restrict__ xP, unsigned short* __restrict__ wsb)
{
    const int t = threadIdx.x;
    if (blockIdx.x < 16) {
        int i = blockIdx.x * 256 + t;      // (o,c) over 4096
        int o = i >> 6, c = i & 63;
        int ks = c >> 5, hi = (c >> 3) & 3, j = c & 7;
        #pragma unroll
        for (int kk = 0; kk < KK_; ++kk)
            wsb[(size_t)(((kk*2 + ks)*4 + hi)*64 + o)*8 + j] =
                f2bf(wgt[(size_t)(o*64 + c)*KK_ + kk]);
    }
    const int b = blockIdx.x & 7;                  // XCD-pinned
    const int p = (blockIdx.x >> 3) * 256 + t;     // padded pixel id
    if (p >= PHW_) return;
    const int py = p / PW_, px = p % PW_;
    const bool interior = (py >= 2) & (py < 2 + H_) & (px >= 2) & (px < 2 + W_);
    const int sp = (py - 2) * W_ + (px - 2);
    const float* xs = x + (size_t)b * C_ * HW_ + sp;
    unsigned pk[32];
    #pragma unroll
    for (int c2 = 0; c2 < 32; ++c2)
        pk[c2] = interior ? packbf2(xs[(size_t)(2*c2) * HW_],
                                    xs[(size_t)(2*c2+1) * HW_]) : 0u;
    uint4v* dst = (uint4v*)(xP + ((size_t)b * PHW_ + p) * C_);
    #pragma unroll
    for (int j = 0; j < 8; ++j) {
        uint4v v;
        v.x = pk[4*j]; v.y = pk[4*j+1]; v.z = pk[4*j+2]; v.w = pk[4*j+3];
        dst[j] = v;
    }
}

// LDS: stg 4 waves x 2048 B ([16px][128B], XOR-swz)   [0, 8192)
//      wl  weight dbuf 2 x 8192 B (fragment-ordered)  [8192, 24576)
//      epilogue aliases [64 o][68 f32] = 17408 B after a barrier
__global__ __launch_bounds__(256, 2)
void dcn_mfma(const unsigned short* __restrict__ xP,
              const float* __restrict__ offs, const float* __restrict__ mask,
              const unsigned short* __restrict__ wsb,
              const float* __restrict__ bias, float* __restrict__ out)
{
    __shared__ __align__(16) char lds[24576];
    char* stg = lds + (threadIdx.x >> 6) * 2048;   // wave-private samples
    char* wl0 = lds + 8192;                        // weight double-buffer

    const int t    = threadIdx.x;
    const int lane = t & 63;
    const int wid  = t >> 6;
    const int bi   = blockIdx.x & 7;               // XCD-pinned
    const int tile = blockIdx.x >> 3;
    const int pixbase = tile * 64;

    const int lr = lane & 15, lg = lane >> 4;      // MFMA fragment coords
    const int s   = lane & 7;                      // 16B slice within line
    const int ph0 = lane >> 3;                     // pixel (h=0); h=1 adds 8
    const int pix0 = pixbase + wid * 16 + ph0;

    const float* offB = offs + (size_t)bi * 18 * HW_;
    const float* mB   = mask + (size_t)bi * 9  * HW_;
    const unsigned short* xB = xP + (size_t)bi * PHW_ * C_ + s * 8;

    f32x4 acc[4] = {};                             // 4 o-tiles x (16o x 16px)

    // corner data + lerp weights, double-buffered across the barrier
    uint4v cor[2][2][4];                           // [slot][h][corner]
    float  w4[2][2][4];                            // [slot][h][corner-weight]
    float  cyN[2], cxN[2], cmN[2];                 // coords for next geom

    // geometry for sample k -> w4[slot] + ISSUE 8 corner loads -> cor[slot]
    auto geom_issue = [&](int k, int slot, float cy0, float cx0, float cm0,
                          float cy1, float cx1, float cm1) {
        float cyv[2] = {cy0, cy1}, cxv[2] = {cx0, cx1}, cmv[2] = {cm0, cm1};
        #pragma unroll
        for (int h = 0; h < 2; ++h) {
            int pixg = pix0 + h * 8;
            int ho = pixg / W_, wo = pixg % W_;
            float py  = (float)(ho - 1 + k / 3) + cyv[h];
            float pxf = (float)(wo - 1 + k % 3) + cxv[h];
            float y0f = floorf(py), x0f = floorf(pxf);
            float ly = py - y0f, lx = pxf - x0f;
            int y0 = min(max((int)y0f, -2), H_ + 1);   // halo-clamped
            int x0 = min(max((int)x0f, -2), W_ + 1);
            float hy = 1.f - ly, hx = 1.f - lx;
            float a = cmv[h] * hy, b2 = cmv[h] * ly;
            w4[slot][h][0] = a * hx;  w4[slot][h][1] = a * lx;
            w4[slot][h][2] = b2 * hx; w4[slot][h][3] = b2 * lx;
            const char* cb = (const char*)(xB +
                (size_t)((y0 + 2) * PW_ + (x0 + 2)) * C_);
            cor[slot][h][0] = *(const uint4v*)(cb);
            cor[slot][h][1] = *(const uint4v*)(cb + 128);
            cor[slot][h][2] = *(const uint4v*)(cb + ROWB);
            cor[slot][h][3] = *(const uint4v*)(cb + ROWB + 128);
        }
    };

    // ---- prologue ----
    {   // weights(0) -> wl[0]
        const uint4v* g = (const uint4v*)(wsb + (size_t)t * 16);
        uint4v g0 = g[0], g1 = g[1];
        char* d = wl0 + t * 32;
        *(uint4v*)d = g0; *(uint4v*)(d + 16) = g1;
    }
    {   // coords(0) -> geom+issue corners(0) -> slot 0
        float a0 = offB[pix0],       a1 = offB[pix0 + 8];
        float b0 = offB[HW_ + pix0], b1 = offB[HW_ + pix0 + 8];
        float c0 = mB[pix0],         c1 = mB[pix0 + 8];
        geom_issue(0, 0, a0, b0, c0, a1, b1, c1);
    }
    // coords(1) -> regs
    #pragma unroll
    for (int h = 0; h < 2; ++h) {
        cyN[h] = offB[(size_t)2 * HW_ + pix0 + h * 8];
        cxN[h] = offB[(size_t)3 * HW_ + pix0 + h * 8];
        cmN[h] = mB[(size_t)1 * HW_ + pix0 + h * 8];
    }
    __syncthreads();   // drains corners(0); weights(0) visible to all waves

    #pragma unroll
    for (int kk = 0; kk < KK_; ++kk) {
        const int cur = kk & 1, nxt = cur ^ 1;

        uint4v wg0, wg1;
        if (kk + 1 < KK_) {
            // weight-stage loads FIRST (so their vmcnt wait excludes corners)
            const uint4v* g = (const uint4v*)(wsb + (size_t)(kk+1)*4096 + t*16);
            wg0 = g[0]; wg1 = g[1];
            // corners(kk+1): issue into cor[nxt]; completed by this iter's
            // barrier drain, overlapped with lerp/MFMA below
            geom_issue(kk + 1, nxt, cyN[0], cxN[0], cmN[0],
                                    cyN[1], cxN[1], cmN[1]);
            __builtin_amdgcn_sched_barrier(0);     // pin issue point
            // coords(kk+2) -> regs (clamped dummy at tail)
            int k2 = (kk + 2 < KK_) ? kk + 2 : KK_ - 1;
            #pragma unroll
            for (int h = 0; h < 2; ++h) {
                cyN[h] = offB[(size_t)(2*k2)   * HW_ + pix0 + h * 8];
                cxN[h] = offB[(size_t)(2*k2+1) * HW_ + pix0 + h * 8];
                cmN[h] = mB[(size_t)k2 * HW_ + pix0 + h * 8];
            }
            // stage weights(kk+1) -> wl[nxt] (waits only its own 2 loads)
            char* d = wl0 + nxt * 8192 + t * 32;
            *(uint4v*)d = wg0; *(uint4v*)(d + 16) = wg1;
        }

        // ---- lerp cor[cur] (completed last barrier) + pack + stg write ----
        #pragma unroll
        for (int h = 0; h < 2; ++h) {
            float w00 = w4[cur][h][0], w01 = w4[cur][h][1];
            float w10 = w4[cur][h][2], w11 = w4[cur][h][3];
            uint4v pk4;
            #pragma unroll
            for (int j = 0; j < 4; ++j) {
                unsigned u0 = cor[cur][h][0][j], u1 = cor[cur][h][1][j];
                unsigned u2 = cor[cur][h][2][j], u3 = cor[cur][h][3][j];
                float lo = fmaf(bflo(u0), w00, fmaf(bflo(u1), w01,
                           fmaf(bflo(u2), w10, bflo(u3) * w11)));
                float hi = fmaf(bfhi(u0), w00, fmaf(bfhi(u1), w01,
                           fmaf(bfhi(u2), w10, bfhi(u3) * w11)));
                pk4[j] = packbf2(lo, hi);
            }
            int pxl = ph0 + h * 8;
            *(uint4v*)(stg + pxl * 128 + ((s * 16) ^ ((pxl & 7) << 4))) = pk4;
        }

        // ---- B-frags (own-wave LDS) + A-frags (wl[cur]) + MFMA ----
        union { uint4v u; short8 s8; } b0, b1;
        b0.u = *(const uint4v*)(stg + lr*128 + ((lg*16     ) ^ ((lr & 7) << 4)));
        b1.u = *(const uint4v*)(stg + lr*128 + ((64 + lg*16) ^ ((lr & 7) << 4)));
        const char* wlc = wl0 + cur * 8192;
        #pragma unroll
        for (int ks = 0; ks < 2; ++ks)
            #pragma unroll
            for (int m = 0; m < 4; ++m) {
                short8 a = *(const short8*)(wlc +
                    (((ks*4 + lg) * 64 + m*16 + lr) << 4));
                acc[m] = __builtin_amdgcn_mfma_f32_16x16x32_bf16(
                             a, ks ? b1.s8 : b0.s8, acc[m], 0, 0, 0);
            }

        // barrier: drains corners(kk+1) into cor[nxt]; publishes wl[nxt]
        if (kk + 1 < KK_) __syncthreads();
    }

    // ---- epilogue: LDS transpose -> float4 full-line coalesced stores ----
    __syncthreads();                 // all waves done with stg/wl before alias
    float* outb = (float*)lds;       // [64 o][68 f32]
    #pragma unroll
    for (int m = 0; m < 4; ++m)
        #pragma unroll
        for (int r = 0; r < 4; ++r)
            outb[(m * 16 + lg * 4 + r) * 68 + wid * 16 + lr] = acc[m][r];
    __syncthreads();
    #pragma unroll
    for (int r = 0; r < 4; ++r) {
        int idx = t + 256 * r;       // 1024 float4 chunks
        int o = idx >> 4, pq = (idx & 15) * 4;
        float4 v = *(const float4*)&outb[o * 68 + pq];
        float bv = bias[o];
        v.x += bv; v.y += bv; v.z += bv; v.w += bv;
        *(float4*)&out[((size_t)bi * O_ + o) * HW_ + pixbase + pq] = v;
    }
}

extern "C" void kernel_launch(void* const* d_in, const int* in_sizes, int n_in,
                              void* d_out, int out_size, void* d_ws, size_t ws_size,
                              hipStream_t stream)
{
    const float* x    = (const float*)d_in[0];
    const float* offs = (const float*)d_in[1];
    const float* mask = (const float*)d_in[2];
    const float* wgt  = (const float*)d_in[3];
    const float* bias = (const float*)d_in[4];
    float* out = (float*)d_out;

    unsigned short* xP  = (unsigned short*)d_ws;                      // 11,075,584 B
    unsigned short* wsb = (unsigned short*)((char*)d_ws + 11534336);  // 73,728 B

    hipLaunchKernelGGL(cvt_kernel, dim3(8 * 43), dim3(256), 0, stream,
                       x, wgt, xP, wsb);
    hipLaunchKernelGGL(dcn_mfma, dim3(B_ * NTILE), dim3(256), 0, stream,
                       xP, offs, mask, wsb, bias, out);
}